// Round 6
// baseline (638.935 us; speedup 1.0000x reference)
//
#include <hip/hip_runtime.h>
#include <hip/hip_bf16.h>

typedef __attribute__((ext_vector_type(8))) short bf16x8;
typedef __attribute__((ext_vector_type(4))) float f32x4;
typedef __attribute__((ext_vector_type(16))) float f32x16;

__device__ __forceinline__ unsigned short f2bf(float f) {
  __hip_bfloat16 h = __float2bfloat16(f);
  return *reinterpret_cast<unsigned short*>(&h);
}
__device__ __forceinline__ float bf2f(unsigned short u) {
  union { unsigned u; float f; } c; c.u = ((unsigned)u) << 16; return c.f;
}

// ---------------------------------------------------------------- pair tables
__global__ void make_pairs(int* __restrict__ pi, int* __restrict__ pj) {
  int i = threadIdx.x;            // 0..63
  if (i >= 63) return;
  int idx = i * 63 - i * (i - 1) / 2;   // pairs before row i
  for (int j = i + 1; j < 64; ++j) { pi[idx] = i; pj[idx] = j; ++idx; }
}

// ---------------------------------------------------------------- f32 -> bf16
__global__ __launch_bounds__(256)
void cvt_bf16(const float* __restrict__ in, unsigned short* __restrict__ out, int n4) {
  for (int idx = blockIdx.x * 256 + threadIdx.x; idx < n4; idx += gridDim.x * 256) {
    float4 x = ((const float4*)in)[idx];
    ushort4 o;
    o.x = f2bf(x.x); o.y = f2bf(x.y); o.z = f2bf(x.z); o.w = f2bf(x.w);
    ((ushort4*)out)[idx] = o;
  }
}

// -------------------------------- W0 [2048,2272] -> bf16 [2048,2304] 0-padded
__global__ __launch_bounds__(256)
void cvt_w0_pad(const float* __restrict__ W0, unsigned short* __restrict__ out) {
  int idx = blockIdx.x * 256 + threadIdx.x;     // row*576 + chunk4
  if (idx >= 2048 * 576) return;
  int row = idx / 576, c = idx - row * 576;
  ushort4 o;
  if (c < 568) {
    float4 x = ((const float4*)(W0 + (size_t)row * 2272))[c];
    o.x = f2bf(x.x); o.y = f2bf(x.y); o.z = f2bf(x.z); o.w = f2bf(x.w);
  } else {
    o = make_ushort4(0, 0, 0, 0);
  }
  ((ushort4*)(out + (size_t)row * 2304))[c] = o;
}

// ------------------- H0 = [xv | xv_i*xv_j/255 | 0-pad]  (stride 2304, bf16)
__global__ __launch_bounds__(256)
void build_h0(const float* __restrict__ xv, const int* __restrict__ pi,
              const int* __restrict__ pj, unsigned short* __restrict__ H0) {
  __shared__ float xs[256];
  int b = blockIdx.x, t = threadIdx.x;
  xs[t] = xv[(size_t)b * 256 + t];
  __syncthreads();
  unsigned short* out = H0 + (size_t)b * 2304;
  out[t] = f2bf(xs[t]);
  for (int p = t; p < 2016; p += 256) {
    float q = xs[pi[p]] * xs[pj[p]] * (1.0f / 255.0f);
    out[256 + p] = f2bf(q);
  }
  if (t < 32) out[2272 + t] = 0;   // K-pad for BK=64 tiling
}

// ===================================================================== GEMM
// C[M,N](bf16) = A[M,K](bf16) * Bw[N,K]^T + bias
// 256x256 tile, 8 waves (2Mx4N), wave tile 128x64, MFMA 32x32x16.
// K-slice ring pipeline (slice=32, ring of 4 = 128K LDS):
//   slice s: ds_read 12 frags -> issue loads for s+3 -> 16 MFMA (setprio)
//   -> counted vmcnt (oldest slice landed) -> s_barrier.  Race-free: slot
//   (s+3)&3 was last READ in slice s-1, separated by the s-start barrier.
// T1 bijective XCD swizzle; T2 swizzle both-sides (addr bits4-5 ^= row bits2-3).
// K % 32 == 0, K/32 >= 4; gridDim.x % 8 == 0.
__global__ __launch_bounds__(512, 1)
void gemm256(const unsigned short* __restrict__ A,
             const unsigned short* __restrict__ Bw,
             const float* __restrict__ bias,
             unsigned short* __restrict__ C,
             int N, int K, int gx) {
  extern __shared__ unsigned char lds[];   // 4 x 32768: slice = A[256][32] | B[256][32]

  // T1: bijective XCD swizzle (gridDim.x % 8 == 0)
  int nwg = gridDim.x;
  int orig = blockIdx.x;
  int wg = (orig & 7) * (nwg >> 3) + (orig >> 3);
  int bx = wg % gx, by = wg / gx;
  const int m0 = by * 256, n0 = bx * 256;

  const int tid = threadIdx.x;
  const int w = tid >> 6, lane = tid & 63;
  const int wr = w >> 2, wc = w & 3;        // 2 x 4 wave grid, wave tile 128x64
  const int l31 = lane & 31, lh = lane >> 5;  // 32x32 operand coords

  const int NS = K >> 5;                    // K-slices of 32

  // --- staging: per thread 2 chunks of A + 2 of B per slice (16B each).
  // write-side source pre-swizzle: chunk bits0-1 ^= chunk bits4-5 (= row bits2-3)
  const int ch0 = tid, ch1 = tid + 512;
  const int sc0 = ch0 ^ ((ch0 >> 4) & 3), sc1 = ch1 ^ ((ch1 >> 4) & 3);
  const int ar0 = sc0 >> 2, ac0 = (sc0 & 3) * 8;
  const int ar1 = sc1 >> 2, ac1 = (sc1 & 3) * 8;

  auto stage = [&](int s) {
    unsigned base = (unsigned)(s & 3) * 32768u;
    int k0 = s << 5;
    const unsigned short* a0 = A + (size_t)(m0 + ar0) * K + k0 + ac0;
    const unsigned short* a1 = A + (size_t)(m0 + ar1) * K + k0 + ac1;
    const unsigned short* b0 = Bw + (size_t)(n0 + ar0) * K + k0 + ac0;
    const unsigned short* b1 = Bw + (size_t)(n0 + ar1) * K + k0 + ac1;
    __builtin_amdgcn_global_load_lds(
        (const __attribute__((address_space(1))) void*)a0,
        (__attribute__((address_space(3))) void*)(lds + base + (unsigned)ch0 * 16u), 16, 0, 0);
    __builtin_amdgcn_global_load_lds(
        (const __attribute__((address_space(1))) void*)a1,
        (__attribute__((address_space(3))) void*)(lds + base + (unsigned)ch1 * 16u), 16, 0, 0);
    __builtin_amdgcn_global_load_lds(
        (const __attribute__((address_space(1))) void*)b0,
        (__attribute__((address_space(3))) void*)(lds + base + 16384u + (unsigned)ch0 * 16u), 16, 0, 0);
    __builtin_amdgcn_global_load_lds(
        (const __attribute__((address_space(1))) void*)b1,
        (__attribute__((address_space(3))) void*)(lds + base + 16384u + (unsigned)ch1 * 16u), 16, 0, 0);
  };

  // swizzled ds_read of 8 bf16 at (row R, byte col cb) within region
  auto ldfrag = [&](unsigned regionBase, int R, int cb) -> bf16x8 {
    unsigned o = (unsigned)(R * 64 + cb);
    o ^= ((o >> 8) & 3u) << 4;              // addr bits4-5 ^= row bits2-3
    return *(const bf16x8*)(lds + regionBase + o);
  };

  f32x16 acc[4][2];
#pragma unroll
  for (int i = 0; i < 4; ++i)
#pragma unroll
    for (int j = 0; j < 2; ++j)
#pragma unroll
      for (int e = 0; e < 16; ++e) acc[i][j][e] = 0.f;

  // ---- prologue: stage slices 0..2, wait for slice 0 (8 = 2 slices remain)
  stage(0); stage(1); stage(2);
  asm volatile("s_waitcnt vmcnt(8)" ::: "memory");
  __builtin_amdgcn_s_barrier();
  __builtin_amdgcn_sched_barrier(0);

  // ---- main loop over K-slices
  for (int s = 0; s < NS; ++s) {
    const unsigned base = (unsigned)(s & 3) * 32768u;
    // A: 4 m-subtiles x 2 k-halves; B: 2 n-subtiles x 2 k-halves
    // 32x32x16 operand: lane holds row l&31, k = (l>>5)*8 + j (8 contiguous)
    bf16x8 af[4][2], bf_[2][2];
#pragma unroll
    for (int mf = 0; mf < 4; ++mf)
#pragma unroll
      for (int kh = 0; kh < 2; ++kh)
        af[mf][kh] = ldfrag(base, wr * 128 + mf * 32 + l31, kh * 32 + lh * 16);
#pragma unroll
    for (int nf = 0; nf < 2; ++nf)
#pragma unroll
      for (int kh = 0; kh < 2; ++kh)
        bf_[nf][kh] = ldfrag(base + 16384u, wc * 64 + nf * 32 + l31, kh * 32 + lh * 16);

    if (s + 3 < NS) stage(s + 3);           // -> slot (s-1)&3, safe after s-barrier

    __builtin_amdgcn_s_setprio(1);
#pragma unroll
    for (int kh = 0; kh < 2; ++kh)
#pragma unroll
      for (int mf = 0; mf < 4; ++mf)
#pragma unroll
        for (int nf = 0; nf < 2; ++nf)
          acc[mf][nf] = __builtin_amdgcn_mfma_f32_32x32x16_bf16(
              af[mf][kh], bf_[nf][kh], acc[mf][nf], 0, 0, 0);
    __builtin_amdgcn_s_setprio(0);

    // counted waits: ensure slice s+1 has landed before the barrier
    if (s + 3 < NS)       asm volatile("s_waitcnt vmcnt(8)" ::: "memory");
    else if (s + 3 == NS) asm volatile("s_waitcnt vmcnt(4)" ::: "memory");
    else if (s + 2 == NS) asm volatile("s_waitcnt vmcnt(0)" ::: "memory");
    __builtin_amdgcn_s_barrier();
    __builtin_amdgcn_sched_barrier(0);
  }

  // ---- epilogue: bias + bf16 store
  // C/D 32x32 layout: col = lane&31, row = (reg&3) + 8*(reg>>2) + 4*(lane>>5)
#pragma unroll
  for (int mf = 0; mf < 4; ++mf) {
#pragma unroll
    for (int nf = 0; nf < 2; ++nf) {
      int gcol = n0 + wc * 64 + nf * 32 + l31;
      float bv = bias[gcol];
#pragma unroll
      for (int reg = 0; reg < 16; ++reg) {
        int row = (reg & 3) + 8 * (reg >> 2) + 4 * lh;
        int grow = m0 + wr * 128 + mf * 32 + row;
        C[(size_t)grow * N + gcol] = f2bf(acc[mf][nf][reg] + bv);
      }
    }
  }
}

// ---------------------------------------------- BN stats (2-stage, bf16 in)
__global__ __launch_bounds__(256)
void bn_partial(const unsigned short* __restrict__ act, float* __restrict__ psum,
                float* __restrict__ psq, int N) {
  int c = (blockIdx.x * 256 + threadIdx.x) * 2;
  int rg = blockIdx.y;                            // 64 row groups of 256 rows
  const unsigned short* p = act + (size_t)rg * 256 * N + c;
  float s0 = 0.f, s1 = 0.f, q0 = 0.f, q1 = 0.f;
  for (int r = 0; r < 256; ++r) {
    unsigned v = *(const unsigned*)(p + (size_t)r * N);
    float x0 = bf2f((unsigned short)(v & 0xffffu));
    float x1 = bf2f((unsigned short)(v >> 16));
    s0 += x0; q0 += x0 * x0;
    s1 += x1; q1 += x1 * x1;
  }
  psum[rg * N + c] = s0; psum[rg * N + c + 1] = s1;
  psq[rg * N + c]  = q0; psq[rg * N + c + 1]  = q1;
}

__global__ __launch_bounds__(256)
void bn_finalize(const float* __restrict__ psum, const float* __restrict__ psq,
                 const float* __restrict__ g, const float* __restrict__ be,
                 float* __restrict__ aout, float* __restrict__ bout, int N) {
  int c = blockIdx.x * 256 + threadIdx.x;
  float s = 0.f, s2 = 0.f;
  for (int rg = 0; rg < 64; ++rg) { s += psum[rg * N + c]; s2 += psq[rg * N + c]; }
  float mean = s * (1.f / 16384.f);
  float var = s2 * (1.f / 16384.f) - mean * mean;
  float a = g[c] * rsqrtf(var + 1e-5f);
  aout[c] = a;
  bout[c] = be[c] - mean * a;
}

// -------------------------- x = relu(x*a[c]+b[c]) in place (bf16, 8/thread)
__global__ __launch_bounds__(256)
void bn_apply(unsigned short* __restrict__ act, const float* __restrict__ a,
              const float* __restrict__ b2, int Nmask, int total8) {
  for (int idx = blockIdx.x * 256 + threadIdx.x; idx < total8; idx += gridDim.x * 256) {
    uint4 v = ((const uint4*)act)[idx];
    int col = (idx << 3) & Nmask;
    unsigned r[4];
    unsigned vv[4] = {v.x, v.y, v.z, v.w};
#pragma unroll
    for (int h = 0; h < 4; ++h) {
      int c0 = col + h * 2;
      float x0 = bf2f((unsigned short)(vv[h] & 0xffffu));
      float x1 = bf2f((unsigned short)(vv[h] >> 16));
      float y0 = fmaxf(fmaf(x0, a[c0], b2[c0]), 0.f);
      float y1 = fmaxf(fmaf(x1, a[c0 + 1], b2[c0 + 1]), 0.f);
      r[h] = (unsigned)f2bf(y0) | ((unsigned)f2bf(y1) << 16);
    }
    ((uint4*)act)[idx] = make_uint4(r[0], r[1], r[2], r[3]);
  }
}

// --------------------------------------------------- out = H3 @ Wout + bout
__global__ __launch_bounds__(256)
void final_out(const unsigned short* __restrict__ H3, const float* __restrict__ Wout,
               const float* __restrict__ bout, float* __restrict__ out) {
  int wv = threadIdx.x >> 6, lane = threadIdx.x & 63;
  int row = blockIdx.x * 4 + wv;
  const unsigned short* h = H3 + (size_t)row * 1024;
  float s = 0.f;
#pragma unroll
  for (int jj = 0; jj < 4; ++jj) {
    int k4 = (jj * 64 + lane) * 4;
    ushort4 v = *(const ushort4*)(h + k4);
    s += bf2f(v.x) * Wout[k4 + 0];
    s += bf2f(v.y) * Wout[k4 + 1];
    s += bf2f(v.z) * Wout[k4 + 2];
    s += bf2f(v.w) * Wout[k4 + 3];
  }
#pragma unroll
  for (int off = 32; off > 0; off >>= 1) s += __shfl_down(s, off);
  if (lane == 0) out[row] = s + bout[0];
}

// ----------------------------------------------------------------- launcher
extern "C" void kernel_launch(void* const* d_in, const int* in_sizes, int n_in,
                              void* d_out, int out_size, void* d_ws, size_t ws_size,
                              hipStream_t stream) {
  const float* xv  = (const float*)d_in[0];
  const float* W0  = (const float*)d_in[1];  const float* b0  = (const float*)d_in[2];
  const float* g0  = (const float*)d_in[3];  const float* be0 = (const float*)d_in[4];
  const float* W1  = (const float*)d_in[5];  const float* b1  = (const float*)d_in[6];
  const float* g1  = (const float*)d_in[7];  const float* be1 = (const float*)d_in[8];
  const float* W2  = (const float*)d_in[9];  const float* b2  = (const float*)d_in[10];
  const float* g2  = (const float*)d_in[11]; const float* be2 = (const float*)d_in[12];
  const float* Wo  = (const float*)d_in[13]; const float* bo  = (const float*)d_in[14];
  float* out = (float*)d_out;
  (void)in_sizes; (void)n_in; (void)out_size;

  char* ws = (char*)d_ws;
  size_t off = 0;
  auto alloc = [&](size_t bytes) {
    char* p = ws + off; off += (bytes + 255) & ~(size_t)255; return p;
  };
  unsigned short* w0b  = (unsigned short*)alloc((size_t)2048 * 2304 * 2);
  unsigned short* w1b  = (unsigned short*)alloc((size_t)2048 * 2048 * 2);
  unsigned short* w2b  = (unsigned short*)alloc((size_t)1024 * 2048 * 2);
  unsigned short* big0 = (unsigned short*)alloc((size_t)16384 * 2304 * 2); // H0 / act1
  unsigned short* big1 = (unsigned short*)alloc((size_t)16384 * 2048 * 2); // act0 / act2
  float* psum = (float*)alloc((size_t)64 * 2048 * 4);
  float* psq  = (float*)alloc((size_t)64 * 2048 * 4);
  float* aarr = (float*)alloc((size_t)2048 * 4);
  float* barr = (float*)alloc((size_t)2048 * 4);
  int* pi = (int*)alloc(2016 * 4);
  int* pj = (int*)alloc(2016 * 4);

  if (off > ws_size) return;   // clean fail instead of OOB fault

  make_pairs<<<1, 64, 0, stream>>>(pi, pj);
  cvt_w0_pad<<<4608, 256, 0, stream>>>(W0, w0b);
  cvt_bf16<<<2048, 256, 0, stream>>>(W1, w1b, 2048 * 2048 / 4);
  cvt_bf16<<<1024, 256, 0, stream>>>(W2, w2b, 1024 * 2048 / 4);
  build_h0<<<16384, 256, 0, stream>>>(xv, pi, pj, big0);

  // Layer 0: [16384,2304p] x [2048,2304p]^T -> big1
  gemm256<<<512, 512, 131072, stream>>>(big0, w0b, b0, big1, 2048, 2304, 8);
  bn_partial<<<dim3(4, 64), 256, 0, stream>>>(big1, psum, psq, 2048);
  bn_finalize<<<8, 256, 0, stream>>>(psum, psq, g0, be0, aarr, barr, 2048);
  bn_apply<<<2048, 256, 0, stream>>>(big1, aarr, barr, 2047, 16384 * 2048 / 8);

  // Layer 1: [16384,2048] x [2048,2048]^T -> big0
  gemm256<<<512, 512, 131072, stream>>>(big1, w1b, b1, big0, 2048, 2048, 8);
  bn_partial<<<dim3(4, 64), 256, 0, stream>>>(big0, psum, psq, 2048);
  bn_finalize<<<8, 256, 0, stream>>>(psum, psq, g1, be1, aarr, barr, 2048);
  bn_apply<<<2048, 256, 0, stream>>>(big0, aarr, barr, 2047, 16384 * 2048 / 8);

  // Layer 2: [16384,2048] x [1024,2048]^T -> big1
  gemm256<<<256, 512, 131072, stream>>>(big0, w2b, b2, big1, 1024, 2048, 4);
  bn_partial<<<dim3(2, 64), 256, 0, stream>>>(big1, psum, psq, 1024);
  bn_finalize<<<4, 256, 0, stream>>>(psum, psq, g2, be2, aarr, barr, 1024);
  bn_apply<<<2048, 256, 0, stream>>>(big1, aarr, barr, 1023, 16384 * 1024 / 8);

  final_out<<<4096, 256, 0, stream>>>(big1, Wo, bo, out);
}

// Round 9
// 586.154 us; speedup vs baseline: 1.0900x; 1.0900x over previous
//
#include <hip/hip_runtime.h>
#include <hip/hip_bf16.h>

typedef __attribute__((ext_vector_type(8))) short bf16x8;
typedef __attribute__((ext_vector_type(4))) float f32x4;
typedef __attribute__((ext_vector_type(16))) float f32x16;

__device__ __forceinline__ unsigned short f2bf(float f) {
  __hip_bfloat16 h = __float2bfloat16(f);
  return *reinterpret_cast<unsigned short*>(&h);
}
__device__ __forceinline__ float bf2f(unsigned short u) {
  union { unsigned u; float f; } c; c.u = ((unsigned)u) << 16; return c.f;
}

// ---------------------------------------------------------------- pair table
__global__ void make_pairs(int2* __restrict__ pp) {
  int i = threadIdx.x;            // 0..63
  if (i >= 63) return;
  int idx = i * 63 - i * (i - 1) / 2;   // pairs before row i
  for (int j = i + 1; j < 64; ++j) { pp[idx] = make_int2(i, j); ++idx; }
}

// ---------------------------------------------------------------- f32 -> bf16
__global__ __launch_bounds__(256)
void cvt_bf16(const float* __restrict__ in, unsigned short* __restrict__ out, int n4) {
  for (int idx = blockIdx.x * 256 + threadIdx.x; idx < n4; idx += gridDim.x * 256) {
    float4 x = ((const float4*)in)[idx];
    ushort4 o;
    o.x = f2bf(x.x); o.y = f2bf(x.y); o.z = f2bf(x.z); o.w = f2bf(x.w);
    ((ushort4*)out)[idx] = o;
  }
}

// -------------------------------- W0 [2048,2272] -> bf16 [2048,2304] 0-padded
__global__ __launch_bounds__(256)
void cvt_w0_pad(const float* __restrict__ W0, unsigned short* __restrict__ out) {
  int idx = blockIdx.x * 256 + threadIdx.x;     // row*576 + chunk4
  if (idx >= 2048 * 576) return;
  int row = idx / 576, c = idx - row * 576;
  ushort4 o;
  if (c < 568) {
    float4 x = ((const float4*)(W0 + (size_t)row * 2272))[c];
    o.x = f2bf(x.x); o.y = f2bf(x.y); o.z = f2bf(x.z); o.w = f2bf(x.w);
  } else {
    o = make_ushort4(0, 0, 0, 0);
  }
  ((ushort4*)(out + (size_t)row * 2304))[c] = o;
}

// ------------- H0 = [xv | xv_i*xv_j/255 | 0-pad] (stride 2304, bf16, 16B st)
__global__ __launch_bounds__(256)
void build_h0(const float* __restrict__ xv, const int2* __restrict__ pp,
              unsigned short* __restrict__ H0) {
  __shared__ float xs[256];
  __shared__ int2 ps[2016];
  int t = threadIdx.x;
  for (int p = t; p < 2016; p += 256) ps[p] = pp[p];
  for (int rb = 0; rb < 8; ++rb) {
    int row = blockIdx.x * 8 + rb;
    __syncthreads();
    if (t < 64) ((float4*)xs)[t] = ((const float4*)(xv + (size_t)row * 256))[t];
    __syncthreads();
    unsigned short* out = H0 + (size_t)row * 2304;
    for (int c = t; c < 288; c += 256) {     // 288 chunks of 8 bf16 (incl. pad)
      unsigned short v[8];
#pragma unroll
      for (int j = 0; j < 8; ++j) {
        int col = c * 8 + j;
        float x;
        if (col < 256) x = xs[col];
        else if (col < 2272) { int2 pr = ps[col - 256]; x = xs[pr.x] * xs[pr.y] * (1.0f / 255.0f); }
        else x = 0.f;
        v[j] = f2bf(x);
      }
      uint4 pk;
      pk.x = (unsigned)v[0] | ((unsigned)v[1] << 16);
      pk.y = (unsigned)v[2] | ((unsigned)v[3] << 16);
      pk.z = (unsigned)v[4] | ((unsigned)v[5] << 16);
      pk.w = (unsigned)v[6] | ((unsigned)v[7] << 16);
      *(uint4*)(out + c * 8) = pk;
    }
  }
}

// ===================================================================== GEMM
// C[M,N](bf16) = A[M,K](bf16) * Bw[N,K]^T + bias ; also emits per-block-row
// BN partial sums (psum/psq[rg=m0/256][col]) from the bf16-rounded outputs.
// 256x256 tile, 8 waves (2Mx4N), wave tile 128x64, MFMA 32x32x16.
// Ring-4 K-slice (32) staging with counted vmcnt; 2-phase slice:
//   P0: read af(mf0,1)+bf | stage A(s+3) | bar | 8 MFMA | bar
//   P1: read af(mf2,3)    | stage B(s+3) | bar | 8 MFMA | vmcnt casc | bar
// T1 bijective XCD swizzle; T2 both-sides swizzle (bits4-5 ^= row bits2-3);
// T5 setprio. K%32==0, K/32>=4; gridDim.x%8==0.
__global__ __launch_bounds__(512, 1)
void gemm256(const unsigned short* __restrict__ A,
             const unsigned short* __restrict__ Bw,
             const float* __restrict__ bias,
             unsigned short* __restrict__ C,
             float* __restrict__ psum, float* __restrict__ psq,
             int N, int K, int gx) {
  extern __shared__ unsigned char lds[];   // 4 x 32768: slice = A[256][32] | B[256][32]

  int nwg = gridDim.x;
  int orig = blockIdx.x;
  int wg = (orig & 7) * (nwg >> 3) + (orig >> 3);
  int bx = wg % gx, by = wg / gx;
  const int m0 = by * 256, n0 = bx * 256;

  const int tid = threadIdx.x;
  const int w = tid >> 6, lane = tid & 63;
  const int wr = w >> 2, wc = w & 3;          // 2 x 4 wave grid
  const int l31 = lane & 31, lh = lane >> 5;

  const int NS = K >> 5;

  // staging geometry (16B chunks, write-side inverse swizzle)
  const int ch0 = tid, ch1 = tid + 512;
  const int sc0 = ch0 ^ ((ch0 >> 4) & 3), sc1 = ch1 ^ ((ch1 >> 4) & 3);
  const int ar0 = sc0 >> 2, ac0 = (sc0 & 3) * 8;
  const int ar1 = sc1 >> 2, ac1 = (sc1 & 3) * 8;

  auto stageA = [&](int s) {
    unsigned base = (unsigned)(s & 3) * 32768u;
    int k0 = s << 5;
    const unsigned short* a0 = A + (size_t)(m0 + ar0) * K + k0 + ac0;
    const unsigned short* a1 = A + (size_t)(m0 + ar1) * K + k0 + ac1;
    __builtin_amdgcn_global_load_lds(
        (const __attribute__((address_space(1))) void*)a0,
        (__attribute__((address_space(3))) void*)(lds + base + (unsigned)ch0 * 16u), 16, 0, 0);
    __builtin_amdgcn_global_load_lds(
        (const __attribute__((address_space(1))) void*)a1,
        (__attribute__((address_space(3))) void*)(lds + base + (unsigned)ch1 * 16u), 16, 0, 0);
  };
  auto stageB = [&](int s) {
    unsigned base = (unsigned)(s & 3) * 32768u + 16384u;
    int k0 = s << 5;
    const unsigned short* b0 = Bw + (size_t)(n0 + ar0) * K + k0 + ac0;
    const unsigned short* b1 = Bw + (size_t)(n0 + ar1) * K + k0 + ac1;
    __builtin_amdgcn_global_load_lds(
        (const __attribute__((address_space(1))) void*)b0,
        (__attribute__((address_space(3))) void*)(lds + base + (unsigned)ch0 * 16u), 16, 0, 0);
    __builtin_amdgcn_global_load_lds(
        (const __attribute__((address_space(1))) void*)b1,
        (__attribute__((address_space(3))) void*)(lds + base + (unsigned)ch1 * 16u), 16, 0, 0);
  };

  auto ldfrag = [&](unsigned regionBase, int R, int cb) -> bf16x8 {
    unsigned o = (unsigned)(R * 64 + cb);
    o ^= ((o >> 8) & 3u) << 4;              // addr bits4-5 ^= row bits2-3
    return *(const bf16x8*)(lds + regionBase + o);
  };

  f32x16 acc[4][2];
#pragma unroll
  for (int i = 0; i < 4; ++i)
#pragma unroll
    for (int j = 0; j < 2; ++j)
#pragma unroll
      for (int e = 0; e < 16; ++e) acc[i][j][e] = 0.f;

  // ---- prologue: stage slices 0..2; wait slice 0 (first 4 loads)
  stageA(0); stageB(0); stageA(1); stageB(1); stageA(2); stageB(2);
  asm volatile("s_waitcnt vmcnt(8)" ::: "memory");
  __builtin_amdgcn_s_barrier();
  __builtin_amdgcn_sched_barrier(0);

  // ---- main loop over K-slices
  for (int s = 0; s < NS; ++s) {
    const unsigned base = (unsigned)(s & 3) * 32768u;
    const bool pf = (s + 3 < NS);

    // ---------------- phase 0: mf 0-1 ----------------
    bf16x8 a0[2][2], bq[2][2];
#pragma unroll
    for (int mf = 0; mf < 2; ++mf)
#pragma unroll
      for (int kh = 0; kh < 2; ++kh)
        a0[mf][kh] = ldfrag(base, wr * 128 + mf * 32 + l31, kh * 32 + lh * 16);
#pragma unroll
    for (int nf = 0; nf < 2; ++nf)
#pragma unroll
      for (int kh = 0; kh < 2; ++kh)
        bq[nf][kh] = ldfrag(base + 16384u, wc * 64 + nf * 32 + l31, kh * 32 + lh * 16);
    if (pf) stageA(s + 3);                  // -> slot (s-1)&3, race-free
    __builtin_amdgcn_s_barrier();
    __builtin_amdgcn_sched_barrier(0);
    __builtin_amdgcn_s_setprio(1);
#pragma unroll
    for (int kh = 0; kh < 2; ++kh)
#pragma unroll
      for (int mf = 0; mf < 2; ++mf)
#pragma unroll
        for (int nf = 0; nf < 2; ++nf)
          acc[mf][nf] = __builtin_amdgcn_mfma_f32_32x32x16_bf16(
              a0[mf][kh], bq[nf][kh], acc[mf][nf], 0, 0, 0);
    __builtin_amdgcn_s_setprio(0);
    __builtin_amdgcn_s_barrier();
    __builtin_amdgcn_sched_barrier(0);

    // ---------------- phase 1: mf 2-3 ----------------
    bf16x8 a1[2][2];
#pragma unroll
    for (int mf = 0; mf < 2; ++mf)
#pragma unroll
      for (int kh = 0; kh < 2; ++kh)
        a1[mf][kh] = ldfrag(base, wr * 128 + (mf + 2) * 32 + l31, kh * 32 + lh * 16);
    if (pf) stageB(s + 3);
    __builtin_amdgcn_s_barrier();
    __builtin_amdgcn_sched_barrier(0);
    __builtin_amdgcn_s_setprio(1);
#pragma unroll
    for (int kh = 0; kh < 2; ++kh)
#pragma unroll
      for (int mf = 0; mf < 2; ++mf)
#pragma unroll
        for (int nf = 0; nf < 2; ++nf)
          acc[mf + 2][nf] = __builtin_amdgcn_mfma_f32_32x32x16_bf16(
              a1[mf][kh], bq[nf][kh], acc[mf + 2][nf], 0, 0, 0);
    __builtin_amdgcn_s_setprio(0);
    if (pf)                asm volatile("s_waitcnt vmcnt(8)" ::: "memory");
    else if (s + 3 == NS)  asm volatile("s_waitcnt vmcnt(4)" ::: "memory");
    else if (s + 2 == NS)  asm volatile("s_waitcnt vmcnt(0)" ::: "memory");
    __builtin_amdgcn_s_barrier();
    __builtin_amdgcn_sched_barrier(0);
  }

  // ---- epilogue: bias + bf16 store + fused BN partial stats
  // C/D 32x32 layout: col = lane&31, row = (reg&3) + 8*(reg>>2) + 4*(lane>>5)
  float* sred = (float*)lds;                // [2][256]
  float* qred = sred + 512;                 // [2][256]
#pragma unroll
  for (int nf = 0; nf < 2; ++nf) {
    int ci = wc * 64 + nf * 32 + l31;
    int gcol = n0 + ci;
    float bv = bias[gcol];
    float s_ = 0.f, q_ = 0.f;
#pragma unroll
    for (int mf = 0; mf < 4; ++mf) {
      int growb = m0 + wr * 128 + mf * 32;
#pragma unroll
      for (int reg = 0; reg < 16; ++reg) {
        int row = (reg & 3) + 8 * (reg >> 2) + 4 * lh;
        unsigned short yb = f2bf(acc[mf][nf][reg] + bv);
        C[(size_t)(growb + row) * N + gcol] = yb;
        float x = bf2f(yb);
        s_ += x; q_ += x * x;
      }
    }
    // lh=0 and lh=1 lanes cover disjoint row halves of the SAME column:
    // reduce across the pair before writing (r7 bug: both wrote same addr).
    s_ += __shfl_xor(s_, 32);
    q_ += __shfl_xor(q_, 32);
    if (lh == 0) {
      sred[wr * 256 + ci] = s_;
      qred[wr * 256 + ci] = q_;
    }
  }
  __syncthreads();
  if (wr == 0) {
#pragma unroll
    for (int nf = 0; nf < 2; ++nf) {
      int ci = wc * 64 + nf * 32 + l31;
      psum[(size_t)by * N + n0 + ci] = sred[ci] + sred[256 + ci];
      psq [(size_t)by * N + n0 + ci] = qred[ci] + qred[256 + ci];
    }
  }
}

// -------------------------------------------------------------- BN finalize
__global__ __launch_bounds__(256)
void bn_finalize(const float* __restrict__ psum, const float* __restrict__ psq,
                 const float* __restrict__ g, const float* __restrict__ be,
                 float* __restrict__ aout, float* __restrict__ bout, int N) {
  int c = blockIdx.x * 256 + threadIdx.x;
  float s = 0.f, s2 = 0.f;
  for (int rg = 0; rg < 64; ++rg) { s += psum[rg * N + c]; s2 += psq[rg * N + c]; }
  float mean = s * (1.f / 16384.f);
  float var = s2 * (1.f / 16384.f) - mean * mean;
  float a = g[c] * rsqrtf(var + 1e-5f);
  aout[c] = a;
  bout[c] = be[c] - mean * a;
}

// -------------------------- x = relu(x*a[c]+b[c]) in place (bf16, 8/thread)
__global__ __launch_bounds__(256)
void bn_apply(unsigned short* __restrict__ act, const float* __restrict__ a,
              const float* __restrict__ b2, int Nmask, int total8) {
  for (int idx = blockIdx.x * 256 + threadIdx.x; idx < total8; idx += gridDim.x * 256) {
    uint4 v = ((const uint4*)act)[idx];
    int col = (idx << 3) & Nmask;
    unsigned r[4];
    unsigned vv[4] = {v.x, v.y, v.z, v.w};
#pragma unroll
    for (int h = 0; h < 4; ++h) {
      int c0 = col + h * 2;
      float x0 = bf2f((unsigned short)(vv[h] & 0xffffu));
      float x1 = bf2f((unsigned short)(vv[h] >> 16));
      float y0 = fmaxf(fmaf(x0, a[c0], b2[c0]), 0.f);
      float y1 = fmaxf(fmaf(x1, a[c0 + 1], b2[c0 + 1]), 0.f);
      r[h] = (unsigned)f2bf(y0) | ((unsigned)f2bf(y1) << 16);
    }
    ((uint4*)act)[idx] = make_uint4(r[0], r[1], r[2], r[3]);
  }
}

// --------------------------------------------------- out = H3 @ Wout + bout
__global__ __launch_bounds__(256)
void final_out(const unsigned short* __restrict__ H3, const float* __restrict__ Wout,
               const float* __restrict__ bout, float* __restrict__ out) {
  int wv = threadIdx.x >> 6, lane = threadIdx.x & 63;
  int row = blockIdx.x * 4 + wv;
  const unsigned short* h = H3 + (size_t)row * 1024;
  float s = 0.f;
#pragma unroll
  for (int jj = 0; jj < 4; ++jj) {
    int k4 = (jj * 64 + lane) * 4;
    ushort4 v = *(const ushort4*)(h + k4);
    s += bf2f(v.x) * Wout[k4 + 0];
    s += bf2f(v.y) * Wout[k4 + 1];
    s += bf2f(v.z) * Wout[k4 + 2];
    s += bf2f(v.w) * Wout[k4 + 3];
  }
#pragma unroll
  for (int off = 32; off > 0; off >>= 1) s += __shfl_down(s, off);
  if (lane == 0) out[row] = s + bout[0];
}

// ----------------------------------------------------------------- launcher
extern "C" void kernel_launch(void* const* d_in, const int* in_sizes, int n_in,
                              void* d_out, int out_size, void* d_ws, size_t ws_size,
                              hipStream_t stream) {
  const float* xv  = (const float*)d_in[0];
  const float* W0  = (const float*)d_in[1];  const float* b0  = (const float*)d_in[2];
  const float* g0  = (const float*)d_in[3];  const float* be0 = (const float*)d_in[4];
  const float* W1  = (const float*)d_in[5];  const float* b1  = (const float*)d_in[6];
  const float* g1  = (const float*)d_in[7];  const float* be1 = (const float*)d_in[8];
  const float* W2  = (const float*)d_in[9];  const float* b2  = (const float*)d_in[10];
  const float* g2  = (const float*)d_in[11]; const float* be2 = (const float*)d_in[12];
  const float* Wo  = (const float*)d_in[13]; const float* bo  = (const float*)d_in[14];
  float* out = (float*)d_out;
  (void)in_sizes; (void)n_in; (void)out_size;

  char* ws = (char*)d_ws;
  size_t off = 0;
  auto alloc = [&](size_t bytes) {
    char* p = ws + off; off += (bytes + 255) & ~(size_t)255; return p;
  };
  unsigned short* w0b  = (unsigned short*)alloc((size_t)2048 * 2304 * 2);
  unsigned short* w1b  = (unsigned short*)alloc((size_t)2048 * 2048 * 2);
  unsigned short* w2b  = (unsigned short*)alloc((size_t)1024 * 2048 * 2);
  unsigned short* big0 = (unsigned short*)alloc((size_t)16384 * 2304 * 2); // H0 / act1
  unsigned short* big1 = (unsigned short*)alloc((size_t)16384 * 2048 * 2); // act0 / act2
  float* psum = (float*)alloc((size_t)64 * 2048 * 4);
  float* psq  = (float*)alloc((size_t)64 * 2048 * 4);
  float* aarr = (float*)alloc((size_t)2048 * 4);
  float* barr = (float*)alloc((size_t)2048 * 4);
  int2* pp = (int2*)alloc(2016 * 8);

  if (off > ws_size) return;   // clean fail instead of OOB fault

  make_pairs<<<1, 64, 0, stream>>>(pp);
  cvt_w0_pad<<<4608, 256, 0, stream>>>(W0, w0b);
  cvt_bf16<<<2048, 256, 0, stream>>>(W1, w1b, 2048 * 2048 / 4);
  cvt_bf16<<<1024, 256, 0, stream>>>(W2, w2b, 1024 * 2048 / 4);
  build_h0<<<2048, 256, 0, stream>>>(xv, pp, big0);

  // Layer 0: [16384,2304p] x [2048,2304p]^T -> big1 (+ fused BN partials)
  gemm256<<<512, 512, 131072, stream>>>(big0, w0b, b0, big1, psum, psq, 2048, 2304, 8);
  bn_finalize<<<8, 256, 0, stream>>>(psum, psq, g0, be0, aarr, barr, 2048);
  bn_apply<<<2048, 256, 0, stream>>>(big1, aarr, barr, 2047, 16384 * 2048 / 8);

  // Layer 1: [16384,2048] x [2048,2048]^T -> big0
  gemm256<<<512, 512, 131072, stream>>>(big1, w1b, b1, big0, psum, psq, 2048, 2048, 8);
  bn_finalize<<<8, 256, 0, stream>>>(psum, psq, g1, be1, aarr, barr, 2048);
  bn_apply<<<2048, 256, 0, stream>>>(big0, aarr, barr, 2047, 16384 * 2048 / 8);

  // Layer 2: [16384,2048] x [1024,2048]^T -> big1
  gemm256<<<256, 512, 131072, stream>>>(big0, w2b, b2, big1, psum, psq, 1024, 2048, 4);
  bn_finalize<<<4, 256, 0, stream>>>(psum, psq, g2, be2, aarr, barr, 1024);
  bn_apply<<<2048, 256, 0, stream>>>(big1, aarr, barr, 1023, 16384 * 1024 / 8);

  final_out<<<4096, 256, 0, stream>>>(big1, Wo, bo, out);
}